// Round 18
// baseline (672.410 us; speedup 1.0000x reference)
//
#include <hip/hip_runtime.h>
#include <hip/hip_bf16.h>

#define MUL_Sc 256
#define DIM_Hc 640
#define IN_COLS 644
#define KF 768
#define NTS 32

#define C0F 0.05103103630798287f
#define INV_SQRT3F 0.57735026918962576f

typedef __attribute__((ext_vector_type(8))) short short8;
typedef __attribute__((ext_vector_type(4))) float f32x4;

#define MFMA(a, b, c) __builtin_amdgcn_mfma_f32_16x16x32_bf16((a), (b), (c), 0, 0, 0)

__device__ __forceinline__ unsigned short f2bf(float x) {
    union { float f; unsigned u; } v; v.f = x;
    unsigned r = v.u + 0x7fffu + ((v.u >> 16) & 1u);   // RNE
    return (unsigned short)(r >> 16);
}

__device__ __forceinline__ void gload_lds16(const unsigned short* g, unsigned short* l) {
    __builtin_amdgcn_global_load_lds((const __attribute__((address_space(1))) void*)g,
                                     (__attribute__((address_space(3))) void*)l, 16, 0, 0);
}

// DCE keepalive for a 128-bit vector (rule 17)
__device__ __forceinline__ void keep8(short8 v) {
    union { short8 s; unsigned u[4]; } t; t.s = v;
    asm volatile("" :: "v"(t.u[0]), "v"(t.u[1]), "v"(t.u[2]), "v"(t.u[3]));
}

// ---- weight prep: fp32 [k][col] -> bf16 transposed [col][k] ----
__global__ void prep_weights(const float* __restrict__ Wss, const float* __restrict__ Wvv,
                             const float* __restrict__ Wssg, const float* __restrict__ Wvvg,
                             const float* __restrict__ Wsv, const float* __restrict__ Wvs,
                             unsigned short* __restrict__ wt) {
    int i = blockIdx.x * 256 + threadIdx.x;
    const int N_SG = 384 * 384;
    const int N_SV = 128 * 256;
    const int N_VS = 128 * 128;
    if (i < N_SG) {
        int col = i / 384, k = i % 384;
        float v;
        if (col < 256) v = (k < 256) ? Wss[k * 256 + col] : Wvv[(k - 256) * 256 + col];
        else { int c = col - 256; v = (k < 256) ? Wssg[k * 128 + c] : Wvvg[(k - 256) * 128 + c]; }
        wt[i] = f2bf(v);
    } else if (i < N_SG + N_SV) {
        int j = i - N_SG; int col = j >> 8, k = j & 255;
        wt[i] = f2bf(Wsv[k * 128 + col]);
    } else if (i < N_SG + N_SV + N_VS) {
        int j = i - N_SG - N_SV; int col = j >> 7, k = j & 127;
        wt[i] = f2bf(Wvs[k * 128 + col]);
    }
}

// ==== kernel 1: din -> pre-swizzled bf16 feature tiles + psv (R15 verbatim, proven) ====
__global__ __launch_bounds__(512, 2)
void convert_feat(const float* __restrict__ din, unsigned short* __restrict__ featg,
                  float* __restrict__ psvg, int N) {
    const int T = blockIdx.x;
    const int tid = threadIdx.x;
    const int g = tid >> 4;
    const int j = tid & 15;
    int n = T * NTS + g; if (n >= N) n = N - 1;
    const float* row = din + (size_t)n * IN_COLS;
    float ps  = row[DIM_Hc];
    float pv0 = row[DIM_Hc + 1], pv1 = row[DIM_Hc + 2], pv2 = row[DIM_Hc + 3];
    if (j == 0 && T * NTS + g < N) {
        float4 pp; pp.x = ps; pp.y = pv0; pp.z = pv1; pp.w = pv2;
        *(float4*)(psvg + 4 * (size_t)(T * NTS + g)) = pp;
    }
    char* fb = (char*)featg + (size_t)T * (NTS * KF * 2);
    const int swz  = (g & 7) << 4;
    const int rowb = g * (KF * 2);
    {
        int c = 16 * j;
        float4 x0 = *(const float4*)(row + c);
        float4 x1 = *(const float4*)(row + c + 4);
        float4 x2 = *(const float4*)(row + c + 8);
        float4 x3 = *(const float4*)(row + c + 12);
        short8 p0, p1;
        p0[0]=(short)f2bf(x0.x); p0[1]=(short)f2bf(x0.y); p0[2]=(short)f2bf(x0.z); p0[3]=(short)f2bf(x0.w);
        p0[4]=(short)f2bf(x1.x); p0[5]=(short)f2bf(x1.y); p0[6]=(short)f2bf(x1.z); p0[7]=(short)f2bf(x1.w);
        p1[0]=(short)f2bf(x2.x); p1[1]=(short)f2bf(x2.y); p1[2]=(short)f2bf(x2.z); p1[3]=(short)f2bf(x2.w);
        p1[4]=(short)f2bf(x3.x); p1[5]=(short)f2bf(x3.y); p1[6]=(short)f2bf(x3.z); p1[7]=(short)f2bf(x3.w);
        *(short8*)(fb + ((rowb + c * 2) ^ swz))       = p0;
        *(short8*)(fb + ((rowb + (c + 8) * 2) ^ swz)) = p1;
    }
    {
        int u0 = 8 * j;
        const float* p = row + MUL_Sc + 3 * u0;
        float e[24];
        #pragma unroll
        for (int q = 0; q < 6; ++q) {
            float4 v = *(const float4*)(p + 4 * q);
            e[4*q+0] = v.x; e[4*q+1] = v.y; e[4*q+2] = v.z; e[4*q+3] = v.w;
        }
        short8 dp, k0, k1, k2;
        #pragma unroll
        for (int m = 0; m < 8; ++m) {
            float a = e[3*m], b = e[3*m+1], c = e[3*m+2];
            dp[m] = (short)f2bf((a * pv0 + b * pv1 + c * pv2) * INV_SQRT3F);
            k0[m] = (short)f2bf(a);
            k1[m] = (short)f2bf(b);
            k2[m] = (short)f2bf(c);
        }
        *(short8*)(fb + ((rowb + (256 + u0) * 2) ^ swz)) = dp;
        *(short8*)(fb + ((rowb + (384 + u0) * 2) ^ swz)) = k0;
        *(short8*)(fb + ((rowb + (512 + u0) * 2) ^ swz)) = k1;
        *(short8*)(fb + ((rowb + (640 + u0) * 2) ^ swz)) = k2;
    }
}

// ==== ABLATION kernel: V0 stage-only / V1 +A-reads / V2 +B-loads / V3 full-compute-no-stores ====
template<int V>
__global__ __launch_bounds__(512, 2)
void gemm_abl(const unsigned short* __restrict__ featg, const float* __restrict__ psvg,
              const unsigned short* __restrict__ wt, const float* __restrict__ bias,
              float* __restrict__ sink, int N) {
    __shared__ unsigned short feat[NTS * KF];
    const int tid = threadIdx.x;
    const int T = blockIdx.x;
    const int n0 = T * NTS;
    {
        const unsigned short* gb = featg + (size_t)T * (NTS * KF);
        unsigned short* lb = feat + (tid >> 6) * 512;
        #pragma unroll
        for (int r = 0; r < 6; ++r)
            gload_lds16(gb + ((size_t)r * 512 + tid) * 8, lb + r * 4096);
    }
    __syncthreads();

    if constexpr (V == 0) {
        sink[(size_t)T * 512 + tid] = (float)feat[tid];
        return;
    }

    const int wave = tid >> 6;
    const int lane = tid & 63;
    const int l15  = lane & 15;
    const int lkb  = (lane >> 4) << 3;
    const int rbase = (lane >> 4) << 2;
    const char* fbr = (const char*)feat;
    const int swzr = (l15 & 7) << 4;

    const unsigned short* WTsg = wt;
    const unsigned short* WTsv = wt + 384 * 384;
    const unsigned short* WTvs = wt + 384 * 384 + 128 * 256;

    if constexpr (V == 1) {   // all A-fragment ds_reads (64 x b128/thread), no B, no MFMA
        #pragma unroll
        for (int ks = 0; ks < 12; ++ks) {          // sg: xs 8 + dot 4
            int kf = ks * 32 + lkb;
            keep8(*(const short8*)(fbr + ((l15 * 1536 + kf * 2) ^ swzr)));
            keep8(*(const short8*)(fbr + (((16 + l15) * 1536 + kf * 2) ^ swzr)));
        }
        #pragma unroll
        for (int ks = 0; ks < 8; ++ks) {           // sv re-reads xs plane
            int kf = ks * 32 + lkb;
            keep8(*(const short8*)(fbr + ((l15 * 1536 + kf * 2) ^ swzr)));
            keep8(*(const short8*)(fbr + (((16 + l15) * 1536 + kf * 2) ^ swzr)));
        }
        #pragma unroll
        for (int ks = 0; ks < 4; ++ks)
        #pragma unroll
        for (int p = 0; p < 3; ++p) {              // vs: xv planes
            int kf = 384 + 128 * p + ks * 32 + lkb;
            keep8(*(const short8*)(fbr + ((l15 * 1536 + kf * 2) ^ swzr)));
            keep8(*(const short8*)(fbr + (((16 + l15) * 1536 + kf * 2) ^ swzr)));
        }
        sink[(size_t)T * 512 + tid] = (float)feat[tid];
        return;
    }

    if constexpr (V == 2) {   // all B weight loads (48 x b128/thread), no A, no MFMA
        #pragma unroll
        for (int ks = 0; ks < 12; ++ks)
        #pragma unroll
        for (int t = 0; t < 3; ++t) {
            int ct = wave + t * 8;
            keep8(*(const short8*)(WTsg + (ct * 16 + l15) * 384 + ks * 32 + lkb));
        }
        #pragma unroll
        for (int ks = 0; ks < 8; ++ks)
            keep8(*(const short8*)(WTsv + (wave * 16 + l15) * 256 + ks * 32 + lkb));
        #pragma unroll
        for (int ks = 0; ks < 4; ++ks)
            keep8(*(const short8*)(WTvs + (wave * 16 + l15) * 128 + ks * 32 + lkb));
        sink[(size_t)T * 512 + tid] = (float)feat[tid];
        return;
    }

    // V == 3: full compute (A+B+MFMA+epilogue VALU), token instead of output stores
    float pss[2][4];
    #pragma unroll
    for (int m = 0; m < 2; ++m)
    #pragma unroll
    for (int i = 0; i < 4; ++i) {
        int n = n0 + m * 16 + rbase + i;
        pss[m][i] = psvg[4 * (size_t)(n < N ? n : N - 1)];
    }
    f32x4 accS[3][2];
    #pragma unroll
    for (int t = 0; t < 3; ++t) { accS[t][0] = (f32x4){0,0,0,0}; accS[t][1] = (f32x4){0,0,0,0}; }
    #pragma unroll
    for (int ks = 0; ks < 8; ++ks) {
        int kf = ks * 32 + lkb;
        short8 a0 = *(const short8*)(fbr + ((l15 * 1536 + kf * 2) ^ swzr));
        short8 a1 = *(const short8*)(fbr + (((16 + l15) * 1536 + kf * 2) ^ swzr));
        #pragma unroll
        for (int t = 0; t < 3; ++t) {
            int ct = wave + t * 8;
            short8 b = *(const short8*)(WTsg + (ct * 16 + l15) * 384 + ks * 32 + lkb);
            accS[t][0] = MFMA(a0, b, accS[t][0]);
            accS[t][1] = MFMA(a1, b, accS[t][1]);
        }
    }
    #pragma unroll
    for (int t = 0; t < 3; ++t)
    #pragma unroll
    for (int m = 0; m < 2; ++m)
    #pragma unroll
    for (int i = 0; i < 4; ++i) accS[t][m][i] *= pss[m][i];
    #pragma unroll
    for (int ks = 0; ks < 4; ++ks) {
        int kf = 256 + ks * 32 + lkb;
        short8 a0 = *(const short8*)(fbr + ((l15 * 1536 + kf * 2) ^ swzr));
        short8 a1 = *(const short8*)(fbr + (((16 + l15) * 1536 + kf * 2) ^ swzr));
        #pragma unroll
        for (int t = 0; t < 3; ++t) {
            int ct = wave + t * 8;
            short8 b = *(const short8*)(WTsg + (ct * 16 + l15) * 384 + 256 + ks * 32 + lkb);
            accS[t][0] = MFMA(a0, b, accS[t][0]);
            accS[t][1] = MFMA(a1, b, accS[t][1]);
        }
    }
    float tok = 0.f;
    #pragma unroll
    for (int t = 0; t < 2; ++t) {
        int col = (wave + t * 8) * 16 + l15;
        float bc = bias[col];
        #pragma unroll
        for (int m = 0; m < 2; ++m)
        #pragma unroll
        for (int i = 0; i < 4; ++i) {
            float sc = C0F * accS[t][m][i] + bc;
            tok += sc / (1.f + __expf(-sc));
        }
    }
    float sgr[2][4];
    #pragma unroll
    for (int m = 0; m < 2; ++m)
    #pragma unroll
    for (int i = 0; i < 4; ++i) sgr[m][i] = 1.f / (1.f + __expf(-C0F * accS[2][m][i]));

    f32x4 accA[2], accV[3][2];
    accA[0] = (f32x4){0,0,0,0}; accA[1] = (f32x4){0,0,0,0};
    #pragma unroll
    for (int k = 0; k < 3; ++k) { accV[k][0] = (f32x4){0,0,0,0}; accV[k][1] = (f32x4){0,0,0,0}; }
    #pragma unroll
    for (int ks = 0; ks < 8; ++ks) {
        int kf = ks * 32 + lkb;
        short8 a0 = *(const short8*)(fbr + ((l15 * 1536 + kf * 2) ^ swzr));
        short8 a1 = *(const short8*)(fbr + (((16 + l15) * 1536 + kf * 2) ^ swzr));
        short8 b = *(const short8*)(WTsv + (wave * 16 + l15) * 256 + ks * 32 + lkb);
        accA[0] = MFMA(a0, b, accA[0]);
        accA[1] = MFMA(a1, b, accA[1]);
    }
    #pragma unroll
    for (int ks = 0; ks < 4; ++ks) {
        short8 b = *(const short8*)(WTvs + (wave * 16 + l15) * 128 + ks * 32 + lkb);
        #pragma unroll
        for (int p = 0; p < 3; ++p) {
            int kf = 384 + 128 * p + ks * 32 + lkb;
            short8 a0 = *(const short8*)(fbr + ((l15 * 1536 + kf * 2) ^ swzr));
            short8 a1 = *(const short8*)(fbr + (((16 + l15) * 1536 + kf * 2) ^ swzr));
            accV[p][0] = MFMA(a0, b, accV[p][0]);
            accV[p][1] = MFMA(a1, b, accV[p][1]);
        }
    }
    #pragma unroll
    for (int m = 0; m < 2; ++m)
    #pragma unroll
    for (int i = 0; i < 4; ++i) {
        int nl = m * 16 + rbase + i;
        int n = n0 + nl;
        size_t pb = 4 * (size_t)(n < N ? n : N - 1);
        float ps  = pss[m][i];
        float pv0 = psvg[pb + 1], pv1 = psvg[pb + 2], pv2 = psvg[pb + 3];
        float sg  = sgr[m][i];
        float av  = accA[m][i];
        tok += C0F * (av * pv0 + accV[0][m][i] * ps) * sg;
        tok += C0F * (av * pv1 + accV[1][m][i] * ps) * sg;
        tok += C0F * (av * pv2 + accV[2][m][i] * ps) * sg;
    }
    sink[(size_t)T * 512 + tid] = tok;
}

// ==== real kernel: R15 gemm_main verbatim (proven 237us, passes) ====
__global__ __launch_bounds__(512, 2)
void gemm_main(const unsigned short* __restrict__ featg, const float* __restrict__ psvg,
               const unsigned short* __restrict__ wt, const float* __restrict__ bias,
               float* __restrict__ out, int N) {
    __shared__ unsigned short feat[NTS * KF];
    const int tid = threadIdx.x;
    const int T = blockIdx.x;
    const int n0 = T * NTS;
    {
        const unsigned short* gb = featg + (size_t)T * (NTS * KF);
        unsigned short* lb = feat + (tid >> 6) * 512;
        #pragma unroll
        for (int r = 0; r < 6; ++r)
            gload_lds16(gb + ((size_t)r * 512 + tid) * 8, lb + r * 4096);
    }
    __syncthreads();

    const int wave = tid >> 6;
    const int lane = tid & 63;
    const int l15  = lane & 15;
    const int lkb  = (lane >> 4) << 3;
    const int rbase = (lane >> 4) << 2;
    const char* fbr = (const char*)feat;
    const int swzr = (l15 & 7) << 4;

    const unsigned short* WTsg = wt;
    const unsigned short* WTsv = wt + 384 * 384;
    const unsigned short* WTvs = wt + 384 * 384 + 128 * 256;

    float bc0 = bias[(wave)     * 16 + l15];
    float bc1 = bias[(wave + 8) * 16 + l15];

    float pss[2][4];
    #pragma unroll
    for (int m = 0; m < 2; ++m)
    #pragma unroll
    for (int i = 0; i < 4; ++i) {
        int n = n0 + m * 16 + rbase + i;
        pss[m][i] = psvg[4 * (size_t)(n < N ? n : N - 1)];
    }

    f32x4 accS[3][2];
    #pragma unroll
    for (int t = 0; t < 3; ++t) { accS[t][0] = (f32x4){0,0,0,0}; accS[t][1] = (f32x4){0,0,0,0}; }
    #pragma unroll
    for (int ks = 0; ks < 8; ++ks) {
        int kf = ks * 32 + lkb;
        short8 a0 = *(const short8*)(fbr + ((l15 * 1536 + kf * 2) ^ swzr));
        short8 a1 = *(const short8*)(fbr + (((16 + l15) * 1536 + kf * 2) ^ swzr));
        #pragma unroll
        for (int t = 0; t < 3; ++t) {
            int ct = wave + t * 8;
            short8 b = *(const short8*)(WTsg + (ct * 16 + l15) * 384 + ks * 32 + lkb);
            accS[t][0] = MFMA(a0, b, accS[t][0]);
            accS[t][1] = MFMA(a1, b, accS[t][1]);
        }
    }
    #pragma unroll
    for (int t = 0; t < 3; ++t)
    #pragma unroll
    for (int m = 0; m < 2; ++m)
    #pragma unroll
    for (int i = 0; i < 4; ++i) accS[t][m][i] *= pss[m][i];
    #pragma unroll
    for (int ks = 0; ks < 4; ++ks) {
        int kf = 256 + ks * 32 + lkb;
        short8 a0 = *(const short8*)(fbr + ((l15 * 1536 + kf * 2) ^ swzr));
        short8 a1 = *(const short8*)(fbr + (((16 + l15) * 1536 + kf * 2) ^ swzr));
        #pragma unroll
        for (int t = 0; t < 3; ++t) {
            int ct = wave + t * 8;
            short8 b = *(const short8*)(WTsg + (ct * 16 + l15) * 384 + 256 + ks * 32 + lkb);
            accS[t][0] = MFMA(a0, b, accS[t][0]);
            accS[t][1] = MFMA(a1, b, accS[t][1]);
        }
    }
    float sgr[2][4];
    #pragma unroll
    for (int m = 0; m < 2; ++m)
    #pragma unroll
    for (int i = 0; i < 4; ++i) sgr[m][i] = 1.f / (1.f + __expf(-C0F * accS[2][m][i]));

    f32x4 accA[2], accV[3][2];
    accA[0] = (f32x4){0,0,0,0}; accA[1] = (f32x4){0,0,0,0};
    #pragma unroll
    for (int k = 0; k < 3; ++k) { accV[k][0] = (f32x4){0,0,0,0}; accV[k][1] = (f32x4){0,0,0,0}; }
    #pragma unroll
    for (int ks = 0; ks < 8; ++ks) {
        int kf = ks * 32 + lkb;
        short8 a0 = *(const short8*)(fbr + ((l15 * 1536 + kf * 2) ^ swzr));
        short8 a1 = *(const short8*)(fbr + (((16 + l15) * 1536 + kf * 2) ^ swzr));
        short8 b = *(const short8*)(WTsv + (wave * 16 + l15) * 256 + ks * 32 + lkb);
        accA[0] = MFMA(a0, b, accA[0]);
        accA[1] = MFMA(a1, b, accA[1]);
    }
    #pragma unroll
    for (int ks = 0; ks < 4; ++ks) {
        short8 b = *(const short8*)(WTvs + (wave * 16 + l15) * 128 + ks * 32 + lkb);
        #pragma unroll
        for (int p = 0; p < 3; ++p) {
            int kf = 384 + 128 * p + ks * 32 + lkb;
            short8 a0 = *(const short8*)(fbr + ((l15 * 1536 + kf * 2) ^ swzr));
            short8 a1 = *(const short8*)(fbr + (((16 + l15) * 1536 + kf * 2) ^ swzr));
            accV[p][0] = MFMA(a0, b, accV[p][0]);
            accV[p][1] = MFMA(a1, b, accV[p][1]);
        }
    }

    __syncthreads();
    float* ldso = (float*)feat;
    const int u = wave * 16 + l15;
    #pragma unroll
    for (int m = 0; m < 2; ++m) {
        #pragma unroll
        for (int t = 0; t < 2; ++t) {
            int col = (wave + t * 8) * 16 + l15;
            float bc = t == 0 ? bc0 : bc1;
            #pragma unroll
            for (int i = 0; i < 4; ++i) {
                int r = rbase + i;
                float sc = C0F * accS[t][m][i] + bc;
                ldso[r * 644 + col] = sc / (1.f + __expf(-sc));
            }
        }
        #pragma unroll
        for (int i = 0; i < 4; ++i) {
            int r = rbase + i;
            int n = n0 + m * 16 + r;
            size_t pb = 4 * (size_t)(n < N ? n : N - 1);
            float ps  = pss[m][i];
            float pv0 = psvg[pb + 1], pv1 = psvg[pb + 2], pv2 = psvg[pb + 3];
            float sg  = sgr[m][i];
            float av  = accA[m][i];
            float* vb = ldso + r * 644 + MUL_Sc + 3 * u;
            vb[0] = C0F * (av * pv0 + accV[0][m][i] * ps) * sg;
            vb[1] = C0F * (av * pv1 + accV[1][m][i] * ps) * sg;
            vb[2] = C0F * (av * pv2 + accV[2][m][i] * ps) * sg;
        }
        __syncthreads();
        {
            int r  = tid >> 5;
            int c0 = (tid & 31) * 20;
            int n  = n0 + m * 16 + r;
            if (n < N) {
                const float* src = ldso + r * 644 + c0;
                float* dst = out + (size_t)n * DIM_Hc + c0;
                #pragma unroll
                for (int q = 0; q < 5; ++q)
                    *(float4*)(dst + 4 * q) = *(const float4*)(src + 4 * q);
            }
        }
        __syncthreads();
    }
}

extern "C" void kernel_launch(void* const* d_in, const int* in_sizes, int n_in,
                              void* d_out, int out_size, void* d_ws, size_t ws_size,
                              hipStream_t stream) {
    const float* din  = (const float*)d_in[0];
    const float* Wss  = (const float*)d_in[1];
    const float* Wvv  = (const float*)d_in[2];
    const float* Wssg = (const float*)d_in[3];
    const float* Wvvg = (const float*)d_in[4];
    const float* Wsv  = (const float*)d_in[5];
    const float* Wvs  = (const float*)d_in[6];
    const float* bias = (const float*)d_in[7];
    float* out = (float*)d_out;
    unsigned short* wt = (unsigned short*)d_ws;

    const size_t WT_SHORTS = 384 * 384 + 128 * 256 + 128 * 128;
    const size_t WT_BYTES = WT_SHORTS * 2;
    if (ws_size < WT_BYTES) return;

    int N = in_sizes[0] / IN_COLS;
    int ntiles = (N + NTS - 1) / NTS;

    prep_weights<<<((int)WT_SHORTS + 255) / 256, 256, 0, stream>>>(Wss, Wvv, Wssg, Wvvg, Wsv, Wvs, wt);

    size_t feat_bytes = (size_t)ntiles * NTS * KF * 2;
    size_t psv_bytes  = (size_t)ntiles * NTS * 4 * sizeof(float);
    size_t need = WT_BYTES + feat_bytes + psv_bytes;
    if (ws_size < need) return;

    unsigned short* featg = wt + WT_SHORTS;
    float* psvg = (float*)((char*)d_ws + WT_BYTES + feat_bytes);

    convert_feat<<<ntiles, 512, 0, stream>>>(din, featg, psvg, N);

    // ---- ablation variants: tokens into d_out (junk; fully overwritten by gemm_main below) ----
    gemm_abl<0><<<ntiles, 512, 0, stream>>>(featg, psvg, wt, bias, out, N);
    gemm_abl<1><<<ntiles, 512, 0, stream>>>(featg, psvg, wt, bias, out, N);
    gemm_abl<2><<<ntiles, 512, 0, stream>>>(featg, psvg, wt, bias, out, N);
    gemm_abl<3><<<ntiles, 512, 0, stream>>>(featg, psvg, wt, bias, out, N);

    // ---- real computation (writes every output element) ----
    gemm_main<<<ntiles, 512, 0, stream>>>(featg, psvg, wt, bias, out, N);
}

// Round 19
// 380.340 us; speedup vs baseline: 1.7679x; 1.7679x over previous
//
#include <hip/hip_runtime.h>
#include <hip/hip_bf16.h>

#define MUL_Sc 256
#define DIM_Hc 640
#define IN_COLS 644
#define NTS 32
#define TILE_SH 24576   // shorts per tile image (48KB): 24 planes x 2 m x 64 lanes x 8

#define C0F 0.05103103630798287f
#define INV_SQRT3F 0.57735026918962576f

typedef __attribute__((ext_vector_type(8))) short short8;
typedef __attribute__((ext_vector_type(4))) float f32x4;

#define MFMA(a, b, c) __builtin_amdgcn_mfma_f32_16x16x32_bf16((a), (b), (c), 0, 0, 0)

__device__ __forceinline__ unsigned short f2bf(float x) {
    union { float f; unsigned u; } v; v.f = x;
    unsigned r = v.u + 0x7fffu + ((v.u >> 16) & 1u);   // RNE
    return (unsigned short)(r >> 16);
}

// ---- weight prep: fp32 [k][col] -> bf16 transposed [col][k] (proven numerics) ----
__global__ void prep_weights(const float* __restrict__ Wss, const float* __restrict__ Wvv,
                             const float* __restrict__ Wssg, const float* __restrict__ Wvvg,
                             const float* __restrict__ Wsv, const float* __restrict__ Wvs,
                             unsigned short* __restrict__ wt) {
    int i = blockIdx.x * 256 + threadIdx.x;
    const int N_SG = 384 * 384;
    const int N_SV = 128 * 256;
    const int N_VS = 128 * 128;
    if (i < N_SG) {
        int col = i / 384, k = i % 384;
        float v;
        if (col < 256) v = (k < 256) ? Wss[k * 256 + col] : Wvv[(k - 256) * 256 + col];
        else { int c = col - 256; v = (k < 256) ? Wssg[k * 128 + c] : Wvvg[(k - 256) * 128 + c]; }
        wt[i] = f2bf(v);
    } else if (i < N_SG + N_SV) {
        int j = i - N_SG; int col = j >> 8, k = j & 255;
        wt[i] = f2bf(Wsv[k * 128 + col]);
    } else if (i < N_SG + N_SV + N_VS) {
        int j = i - N_SG - N_SV; int col = j >> 7, k = j & 127;
        wt[i] = f2bf(Wvs[k * 128 + col]);
    }
}

// ==== kernel 1: din -> fragment-plane tile images + psv (R15 math verbatim, new layout) ====
// plane p: 0..7 xs(kf=32p) | 8..11 dot(kf=256+32(p-8)) | 12..23 xv(kf=384+128*((p-12)/4)+32*((p-12)%4))
// fragment (p, m, lane) = feat_row[m*16+(lane&15)], elems kf(p)+(lane>>4)*8 .. +7
__global__ __launch_bounds__(512, 2)
void convert_feat2(const float* __restrict__ din, unsigned short* __restrict__ featg,
                   float* __restrict__ psvg, int N) {
    const int T = blockIdx.x;
    const int tid = threadIdx.x;
    const int g = tid >> 4;       // local node 0..31
    const int j = tid & 15;       // 16 threads per node
    int n = T * NTS + g; if (n >= N) n = N - 1;
    const float* row = din + (size_t)n * IN_COLS;
    float ps  = row[DIM_Hc];
    float pv0 = row[DIM_Hc + 1], pv1 = row[DIM_Hc + 2], pv2 = row[DIM_Hc + 3];
    if (j == 0 && T * NTS + g < N) {
        float4 pp; pp.x = ps; pp.y = pv0; pp.z = pv1; pp.w = pv2;
        *(float4*)(psvg + 4 * (size_t)(T * NTS + g)) = pp;
    }
    short8* dst = (short8*)(featg + (size_t)T * TILE_SH);
    const int mnode = g >> 4;
    const int g15 = g & 15;

    auto put = [&](int e0, short8 v) {
        int p, rel;
        if (e0 < 256)      { p = e0 >> 5; rel = e0 & 31; }
        else if (e0 < 384) { int r = e0 - 256; p = 8 + (r >> 5); rel = r & 31; }
        else               { int r = e0 - 384; int pp = r >> 7; int q = r & 127;
                             p = 12 + pp * 4 + (q >> 5); rel = q & 31; }
        int lane = ((rel >> 3) << 4) | g15;
        dst[p * 128 + mnode * 64 + lane] = v;
    };

    {   // xs: 16 consecutive elems per thread
        int c = 16 * j;
        float4 x0 = *(const float4*)(row + c);
        float4 x1 = *(const float4*)(row + c + 4);
        float4 x2 = *(const float4*)(row + c + 8);
        float4 x3 = *(const float4*)(row + c + 12);
        short8 p0, p1;
        p0[0]=(short)f2bf(x0.x); p0[1]=(short)f2bf(x0.y); p0[2]=(short)f2bf(x0.z); p0[3]=(short)f2bf(x0.w);
        p0[4]=(short)f2bf(x1.x); p0[5]=(short)f2bf(x1.y); p0[6]=(short)f2bf(x1.z); p0[7]=(short)f2bf(x1.w);
        p1[0]=(short)f2bf(x2.x); p1[1]=(short)f2bf(x2.y); p1[2]=(short)f2bf(x2.z); p1[3]=(short)f2bf(x2.w);
        p1[4]=(short)f2bf(x3.x); p1[5]=(short)f2bf(x3.y); p1[6]=(short)f2bf(x3.z); p1[7]=(short)f2bf(x3.w);
        put(c, p0);
        put(c + 8, p1);
    }
    {   // xv: 8 consecutive u per thread -> dot + 3 k-planes
        int u0 = 8 * j;
        const float* p = row + MUL_Sc + 3 * u0;
        float e[24];
        #pragma unroll
        for (int q = 0; q < 6; ++q) {
            float4 v = *(const float4*)(p + 4 * q);
            e[4*q+0] = v.x; e[4*q+1] = v.y; e[4*q+2] = v.z; e[4*q+3] = v.w;
        }
        short8 dp, k0, k1, k2;
        #pragma unroll
        for (int m = 0; m < 8; ++m) {
            float a = e[3*m], b = e[3*m+1], c = e[3*m+2];
            dp[m] = (short)f2bf((a * pv0 + b * pv1 + c * pv2) * INV_SQRT3F);
            k0[m] = (short)f2bf(a);
            k1[m] = (short)f2bf(b);
            k2[m] = (short)f2bf(c);
        }
        put(256 + u0, dp);
        put(384 + u0, k0);
        put(512 + u0, k1);
        put(640 + u0, k2);
    }
}

// ==== kernel 2: ZERO LDS, ZERO barriers — A-fragments direct from global, scattered stores ====
__global__ __launch_bounds__(512, 4)
void gemm2(const unsigned short* __restrict__ featg, const float* __restrict__ psvg,
           const unsigned short* __restrict__ wt, const float* __restrict__ bias,
           float* __restrict__ out, int N) {
    const int tid = threadIdx.x;
    const int T = blockIdx.x;
    const int n0 = T * NTS;

    const int wave = tid >> 6;
    const int lane = tid & 63;
    const int l15  = lane & 15;
    const int lkb  = (lane >> 4) << 3;
    const int rbase = (lane >> 4) << 2;

    const short8* Af = (const short8*)(featg + (size_t)T * TILE_SH);

    const unsigned short* WTsg = wt;
    const unsigned short* WTsv = wt + 384 * 384;
    const unsigned short* WTvs = wt + 384 * 384 + 128 * 256;

    float pss[2][4];
    #pragma unroll
    for (int m = 0; m < 2; ++m)
    #pragma unroll
    for (int i = 0; i < 4; ++i) {
        int n = n0 + m * 16 + rbase + i;
        pss[m][i] = psvg[4 * (size_t)(n < N ? n : N - 1)];
    }

    // ---- sg GEMM: t=0,1 scal col-tiles, t=2 gate col-tile ----
    f32x4 accS[3][2];
    #pragma unroll
    for (int t = 0; t < 3; ++t) { accS[t][0] = (f32x4){0,0,0,0}; accS[t][1] = (f32x4){0,0,0,0}; }

    #pragma unroll
    for (int ks = 0; ks < 8; ++ks) {      // xs part K=256 (planes 0..7)
        short8 a0 = Af[ks * 128 + lane];
        short8 a1 = Af[ks * 128 + 64 + lane];
        #pragma unroll
        for (int t = 0; t < 3; ++t) {
            int ct = wave + t * 8;        // t=2 -> gate cols 256+wave*16
            short8 b = *(const short8*)(WTsg + (ct * 16 + l15) * 384 + ks * 32 + lkb);
            accS[t][0] = MFMA(a0, b, accS[t][0]);
            accS[t][1] = MFMA(a1, b, accS[t][1]);
        }
    }
    #pragma unroll
    for (int t = 0; t < 3; ++t)
    #pragma unroll
    for (int m = 0; m < 2; ++m)
    #pragma unroll
    for (int i = 0; i < 4; ++i) accS[t][m][i] *= pss[m][i];
    #pragma unroll
    for (int ks = 0; ks < 4; ++ks) {      // dot part K=128 (planes 8..11)
        short8 a0 = Af[(8 + ks) * 128 + lane];
        short8 a1 = Af[(8 + ks) * 128 + 64 + lane];
        #pragma unroll
        for (int t = 0; t < 3; ++t) {
            int ct = wave + t * 8;
            short8 b = *(const short8*)(WTsg + (ct * 16 + l15) * 384 + 256 + ks * 32 + lkb);
            accS[t][0] = MFMA(a0, b, accS[t][0]);
            accS[t][1] = MFMA(a1, b, accS[t][1]);
        }
    }

    // ---- scal epilogue: silu -> global (scattered) ----
    #pragma unroll
    for (int t = 0; t < 2; ++t) {
        int col = (wave + t * 8) * 16 + l15;
        float bc = bias[col];
        #pragma unroll
        for (int m = 0; m < 2; ++m)
        #pragma unroll
        for (int i = 0; i < 4; ++i) {
            int n = n0 + m * 16 + rbase + i;
            if (n < N) {
                float sc = C0F * accS[t][m][i] + bc;
                out[(size_t)n * DIM_Hc + col] = sc / (1.f + __expf(-sc));
            }
        }
    }
    // gate -> sigmoid in registers (gate col wave*16+l15 == vec u-tile col)
    float sgr[2][4];
    #pragma unroll
    for (int m = 0; m < 2; ++m)
    #pragma unroll
    for (int i = 0; i < 4; ++i) sgr[m][i] = 1.f / (1.f + __expf(-C0F * accS[2][m][i]));

    // ---- vec GEMMs: a1 (xs planes again, K=256) + v2_k (xv planes, K=128 x3) ----
    f32x4 accA[2], accV[3][2];
    accA[0] = (f32x4){0,0,0,0}; accA[1] = (f32x4){0,0,0,0};
    #pragma unroll
    for (int k = 0; k < 3; ++k) { accV[k][0] = (f32x4){0,0,0,0}; accV[k][1] = (f32x4){0,0,0,0}; }

    #pragma unroll
    for (int ks = 0; ks < 8; ++ks) {
        short8 a0 = Af[ks * 128 + lane];
        short8 a1 = Af[ks * 128 + 64 + lane];
        short8 b = *(const short8*)(WTsv + (wave * 16 + l15) * 256 + ks * 32 + lkb);
        accA[0] = MFMA(a0, b, accA[0]);
        accA[1] = MFMA(a1, b, accA[1]);
    }
    #pragma unroll
    for (int ks = 0; ks < 4; ++ks) {
        short8 b = *(const short8*)(WTvs + (wave * 16 + l15) * 128 + ks * 32 + lkb);
        #pragma unroll
        for (int p = 0; p < 3; ++p) {
            short8 a0 = Af[(12 + p * 4 + ks) * 128 + lane];
            short8 a1 = Af[(12 + p * 4 + ks) * 128 + 64 + lane];
            accV[p][0] = MFMA(a0, b, accV[p][0]);
            accV[p][1] = MFMA(a1, b, accV[p][1]);
        }
    }

    // ---- vec epilogue: vec = C0*(a1*pv + v2*ps) * sigmoid(gate) (scattered) ----
    {
        int u = wave * 16 + l15;
        #pragma unroll
        for (int m = 0; m < 2; ++m)
        #pragma unroll
        for (int i = 0; i < 4; ++i) {
            int nl = m * 16 + rbase + i;
            int n = n0 + nl;
            if (n >= N) continue;
            size_t pb = 4 * (size_t)n;
            float ps  = pss[m][i];
            float pv0 = psvg[pb + 1], pv1 = psvg[pb + 2], pv2 = psvg[pb + 3];
            float sg  = sgr[m][i];
            float av  = accA[m][i];
            size_t ob = (size_t)n * DIM_Hc + MUL_Sc + 3 * u;
            out[ob + 0] = C0F * (av * pv0 + accV[0][m][i] * ps) * sg;
            out[ob + 1] = C0F * (av * pv1 + accV[1][m][i] * ps) * sg;
            out[ob + 2] = C0F * (av * pv2 + accV[2][m][i] * ps) * sg;
        }
    }
}

extern "C" void kernel_launch(void* const* d_in, const int* in_sizes, int n_in,
                              void* d_out, int out_size, void* d_ws, size_t ws_size,
                              hipStream_t stream) {
    const float* din  = (const float*)d_in[0];
    const float* Wss  = (const float*)d_in[1];
    const float* Wvv  = (const float*)d_in[2];
    const float* Wssg = (const float*)d_in[3];
    const float* Wvvg = (const float*)d_in[4];
    const float* Wsv  = (const float*)d_in[5];
    const float* Wvs  = (const float*)d_in[6];
    const float* bias = (const float*)d_in[7];
    float* out = (float*)d_out;
    unsigned short* wt = (unsigned short*)d_ws;

    const size_t WT_SHORTS = 384 * 384 + 128 * 256 + 128 * 128;
    const size_t WT_BYTES = WT_SHORTS * 2;
    if (ws_size < WT_BYTES) return;

    int N = in_sizes[0] / IN_COLS;
    int ntiles = (N + NTS - 1) / NTS;

    prep_weights<<<((int)WT_SHORTS + 255) / 256, 256, 0, stream>>>(Wss, Wvv, Wssg, Wvvg, Wsv, Wvs, wt);

    size_t feat_bytes = (size_t)ntiles * TILE_SH * 2;
    size_t psv_bytes  = (size_t)ntiles * NTS * 4 * sizeof(float);
    size_t need = WT_BYTES + feat_bytes + psv_bytes;
    if (ws_size < need) return;   // N=100000 -> ~156MB, expected to fit

    unsigned short* featg = wt + WT_SHORTS;
    float* psvg = (float*)((char*)d_ws + WT_BYTES + feat_bytes);

    convert_feat2<<<ntiles, 512, 0, stream>>>(din, featg, psvg, N);
    gemm2<<<ntiles, 512, 0, stream>>>(featg, psvg, wt, bias, out, N);
}

// Round 20
// 298.347 us; speedup vs baseline: 2.2538x; 1.2748x over previous
//
#include <hip/hip_runtime.h>
#include <hip/hip_bf16.h>

#define MUL_Sc 256
#define DIM_Hc 640
#define IN_COLS 644
#define KF 768
#define NTS 32
#define GRIDB 256

#define C0F 0.05103103630798287f
#define INV_SQRT3F 0.57735026918962576f

typedef __attribute__((ext_vector_type(8))) short short8;
typedef __attribute__((ext_vector_type(4))) float f32x4;

#define MFMA(a, b, c) __builtin_amdgcn_mfma_f32_16x16x32_bf16((a), (b), (c), 0, 0, 0)

__device__ __forceinline__ unsigned short f2bf(float x) {
    union { float f; unsigned u; } v; v.f = x;
    unsigned r = v.u + 0x7fffu + ((v.u >> 16) & 1u);   // RNE
    return (unsigned short)(r >> 16);
}

__device__ __forceinline__ void gload_lds16(const unsigned short* g, unsigned short* l) {
    __builtin_amdgcn_global_load_lds((const __attribute__((address_space(1))) void*)g,
                                     (__attribute__((address_space(3))) void*)l, 16, 0, 0);
}

// ---- weight prep: fp32 [k][col] -> bf16 transposed [col][k] (proven numerics) ----
__global__ void prep_weights(const float* __restrict__ Wss, const float* __restrict__ Wvv,
                             const float* __restrict__ Wssg, const float* __restrict__ Wvvg,
                             const float* __restrict__ Wsv, const float* __restrict__ Wvs,
                             unsigned short* __restrict__ wt) {
    int i = blockIdx.x * 256 + threadIdx.x;
    const int N_SG = 384 * 384;
    const int N_SV = 128 * 256;
    const int N_VS = 128 * 128;
    if (i < N_SG) {
        int col = i / 384, k = i % 384;
        float v;
        if (col < 256) v = (k < 256) ? Wss[k * 256 + col] : Wvv[(k - 256) * 256 + col];
        else { int c = col - 256; v = (k < 256) ? Wssg[k * 128 + c] : Wvvg[(k - 256) * 128 + c]; }
        wt[i] = f2bf(v);
    } else if (i < N_SG + N_SV) {
        int j = i - N_SG; int col = j >> 8, k = j & 255;
        wt[i] = f2bf(Wsv[k * 128 + col]);
    } else if (i < N_SG + N_SV + N_VS) {
        int j = i - N_SG - N_SV; int col = j >> 7, k = j & 127;
        wt[i] = f2bf(Wvs[k * 128 + col]);
    }
}

// ==== kernel 1: din -> pre-swizzled bf16 feature tiles + psv (R15 verbatim, proven ~70us) ====
__global__ __launch_bounds__(512, 2)
void convert_feat(const float* __restrict__ din, unsigned short* __restrict__ featg,
                  float* __restrict__ psvg, int N) {
    const int T = blockIdx.x;
    const int tid = threadIdx.x;
    const int g = tid >> 4;
    const int j = tid & 15;
    int n = T * NTS + g; if (n >= N) n = N - 1;
    const float* row = din + (size_t)n * IN_COLS;
    float ps  = row[DIM_Hc];
    float pv0 = row[DIM_Hc + 1], pv1 = row[DIM_Hc + 2], pv2 = row[DIM_Hc + 3];
    if (j == 0 && T * NTS + g < N) {
        float4 pp; pp.x = ps; pp.y = pv0; pp.z = pv1; pp.w = pv2;
        *(float4*)(psvg + 4 * (size_t)(T * NTS + g)) = pp;
    }
    char* fb = (char*)featg + (size_t)T * (NTS * KF * 2);
    const int swz  = (g & 7) << 4;
    const int rowb = g * (KF * 2);
    {
        int c = 16 * j;
        float4 x0 = *(const float4*)(row + c);
        float4 x1 = *(const float4*)(row + c + 4);
        float4 x2 = *(const float4*)(row + c + 8);
        float4 x3 = *(const float4*)(row + c + 12);
        short8 p0, p1;
        p0[0]=(short)f2bf(x0.x); p0[1]=(short)f2bf(x0.y); p0[2]=(short)f2bf(x0.z); p0[3]=(short)f2bf(x0.w);
        p0[4]=(short)f2bf(x1.x); p0[5]=(short)f2bf(x1.y); p0[6]=(short)f2bf(x1.z); p0[7]=(short)f2bf(x1.w);
        p1[0]=(short)f2bf(x2.x); p1[1]=(short)f2bf(x2.y); p1[2]=(short)f2bf(x2.z); p1[3]=(short)f2bf(x2.w);
        p1[4]=(short)f2bf(x3.x); p1[5]=(short)f2bf(x3.y); p1[6]=(short)f2bf(x3.z); p1[7]=(short)f2bf(x3.w);
        *(short8*)(fb + ((rowb + c * 2) ^ swz))       = p0;
        *(short8*)(fb + ((rowb + (c + 8) * 2) ^ swz)) = p1;
    }
    {
        int u0 = 8 * j;
        const float* p = row + MUL_Sc + 3 * u0;
        float e[24];
        #pragma unroll
        for (int q = 0; q < 6; ++q) {
            float4 v = *(const float4*)(p + 4 * q);
            e[4*q+0] = v.x; e[4*q+1] = v.y; e[4*q+2] = v.z; e[4*q+3] = v.w;
        }
        short8 dp, k0, k1, k2;
        #pragma unroll
        for (int m = 0; m < 8; ++m) {
            float a = e[3*m], b = e[3*m+1], c = e[3*m+2];
            dp[m] = (short)f2bf((a * pv0 + b * pv1 + c * pv2) * INV_SQRT3F);
            k0[m] = (short)f2bf(a);
            k1[m] = (short)f2bf(b);
            k2[m] = (short)f2bf(c);
        }
        *(short8*)(fb + ((rowb + (256 + u0) * 2) ^ swz)) = dp;
        *(short8*)(fb + ((rowb + (384 + u0) * 2) ^ swz)) = k0;
        *(short8*)(fb + ((rowb + (512 + u0) * 2) ^ swz)) = k1;
        *(short8*)(fb + ((rowb + (640 + u0) * 2) ^ swz)) = k2;
    }
}

// ==== kernel 2: persistent, dbuf LDS, counted-vmcnt async pipeline, 1 raw barrier/tile ====
__global__ __launch_bounds__(512, 1)
void gemm_pers(const unsigned short* __restrict__ featg, const float* __restrict__ psvg,
               const unsigned short* __restrict__ wt, const float* __restrict__ bias,
               float* __restrict__ out, int N, int ntiles) {
    __shared__ unsigned short feat[2][NTS * KF];   // 2 x 48 KB

    const int tid = threadIdx.x;
    const int T0 = blockIdx.x;

    const int wave = tid >> 6;
    const int lane = tid & 63;
    const int l15  = lane & 15;
    const int lkb  = (lane >> 4) << 3;
    const int rbase = (lane >> 4) << 2;
    const int swzr = (l15 & 7) << 4;

    const unsigned short* WTsg = wt;
    const unsigned short* WTsv = wt + 384 * 384;
    const unsigned short* WTvs = wt + 384 * 384 + 128 * 256;

    float bc0 = bias[(wave)     * 16 + l15];
    float bc1 = bias[(wave + 8) * 16 + l15];

    auto stage = [&](int b, int T) {
        const unsigned short* gb = featg + (size_t)T * (NTS * KF);
        unsigned short* lb = &feat[b][0] + wave * 512;
        #pragma unroll
        for (int r = 0; r < 6; ++r)
            gload_lds16(gb + ((size_t)r * 512 + tid) * 8, lb + r * 4096);
    };

    if (T0 < ntiles) stage(0, T0);
    int cur = 0;

    for (int t = T0; t < ntiles; t += GRIDB) {
        // wait own staging loads (and stray stores), then sync waves: buf[cur] fully ready
        asm volatile("s_waitcnt vmcnt(0)" ::: "memory");
        __builtin_amdgcn_sched_barrier(0);
        asm volatile("s_barrier" ::: "memory");
        __builtin_amdgcn_sched_barrier(0);

        const char* fbr = (const char*)&feat[cur][0];
        const int n0 = t * NTS;
        const int nx = t + GRIDB;

        float pss[2][4];
        #pragma unroll
        for (int m = 0; m < 2; ++m)
        #pragma unroll
        for (int i = 0; i < 4; ++i) {
            int n = n0 + m * 16 + rbase + i;
            pss[m][i] = psvg[4 * (size_t)(n < N ? n : N - 1)];
        }

        // ---- sg GEMM ----
        f32x4 accS[3][2];
        #pragma unroll
        for (int tt = 0; tt < 3; ++tt) { accS[tt][0] = (f32x4){0,0,0,0}; accS[tt][1] = (f32x4){0,0,0,0}; }
        #pragma unroll
        for (int ks = 0; ks < 8; ++ks) {
            int kf = ks * 32 + lkb;
            short8 a0 = *(const short8*)(fbr + ((l15 * 1536 + kf * 2) ^ swzr));
            short8 a1 = *(const short8*)(fbr + (((16 + l15) * 1536 + kf * 2) ^ swzr));
            #pragma unroll
            for (int tt = 0; tt < 3; ++tt) {
                int ct = wave + tt * 8;
                short8 b = *(const short8*)(WTsg + (ct * 16 + l15) * 384 + ks * 32 + lkb);
                accS[tt][0] = MFMA(a0, b, accS[tt][0]);
                accS[tt][1] = MFMA(a1, b, accS[tt][1]);
            }
        }
        #pragma unroll
        for (int tt = 0; tt < 3; ++tt)
        #pragma unroll
        for (int m = 0; m < 2; ++m)
        #pragma unroll
        for (int i = 0; i < 4; ++i) accS[tt][m][i] *= pss[m][i];
        #pragma unroll
        for (int ks = 0; ks < 4; ++ks) {
            int kf = 256 + ks * 32 + lkb;
            short8 a0 = *(const short8*)(fbr + ((l15 * 1536 + kf * 2) ^ swzr));
            short8 a1 = *(const short8*)(fbr + (((16 + l15) * 1536 + kf * 2) ^ swzr));
            #pragma unroll
            for (int tt = 0; tt < 3; ++tt) {
                int ct = wave + tt * 8;
                short8 b = *(const short8*)(WTsg + (ct * 16 + l15) * 384 + 256 + ks * 32 + lkb);
                accS[tt][0] = MFMA(a0, b, accS[tt][0]);
                accS[tt][1] = MFMA(a1, b, accS[tt][1]);
            }
        }

        // ---- scal epilogue (scattered stores) ----
        #pragma unroll
        for (int tt = 0; tt < 2; ++tt) {
            int col = (wave + tt * 8) * 16 + l15;
            float bc = tt == 0 ? bc0 : bc1;
            #pragma unroll
            for (int m = 0; m < 2; ++m)
            #pragma unroll
            for (int i = 0; i < 4; ++i) {
                int n = n0 + m * 16 + rbase + i;
                if (n < N) {
                    float sc = C0F * accS[tt][m][i] + bc;
                    out[(size_t)n * DIM_Hc + col] = sc / (1.f + __expf(-sc));
                }
            }
        }
        float sgr[2][4];
        #pragma unroll
        for (int m = 0; m < 2; ++m)
        #pragma unroll
        for (int i = 0; i < 4; ++i) sgr[m][i] = 1.f / (1.f + __expf(-C0F * accS[2][m][i]));

        // ---- async stage of NEXT tile into buf[cur^1] (0 VGPR, stays in flight) ----
        if (nx < ntiles) {
            __builtin_amdgcn_sched_barrier(0);
            stage(cur ^ 1, nx);
            __builtin_amdgcn_sched_barrier(0);
        }

        // ---- vec GEMMs ----
        f32x4 accA[2], accV[3][2];
        accA[0] = (f32x4){0,0,0,0}; accA[1] = (f32x4){0,0,0,0};
        #pragma unroll
        for (int k = 0; k < 3; ++k) { accV[k][0] = (f32x4){0,0,0,0}; accV[k][1] = (f32x4){0,0,0,0}; }
        #pragma unroll
        for (int ks = 0; ks < 8; ++ks) {
            int kf = ks * 32 + lkb;
            short8 a0 = *(const short8*)(fbr + ((l15 * 1536 + kf * 2) ^ swzr));
            short8 a1 = *(const short8*)(fbr + (((16 + l15) * 1536 + kf * 2) ^ swzr));
            short8 b = *(const short8*)(WTsv + (wave * 16 + l15) * 256 + ks * 32 + lkb);
            accA[0] = MFMA(a0, b, accA[0]);
            accA[1] = MFMA(a1, b, accA[1]);
        }
        #pragma unroll
        for (int ks = 0; ks < 4; ++ks) {
            short8 b = *(const short8*)(WTvs + (wave * 16 + l15) * 128 + ks * 32 + lkb);
            #pragma unroll
            for (int p = 0; p < 3; ++p) {
                int kf = 384 + 128 * p + ks * 32 + lkb;
                short8 a0 = *(const short8*)(fbr + ((l15 * 1536 + kf * 2) ^ swzr));
                short8 a1 = *(const short8*)(fbr + (((16 + l15) * 1536 + kf * 2) ^ swzr));
                accV[p][0] = MFMA(a0, b, accV[p][0]);
                accV[p][1] = MFMA(a1, b, accV[p][1]);
            }
        }

        // ---- vec epilogue (scattered stores) ----
        {
            int u = wave * 16 + l15;
            #pragma unroll
            for (int m = 0; m < 2; ++m)
            #pragma unroll
            for (int i = 0; i < 4; ++i) {
                int nl = m * 16 + rbase + i;
                int n = n0 + nl;
                if (n >= N) continue;
                size_t pb = 4 * (size_t)n;
                float ps  = pss[m][i];
                float pv0 = psvg[pb + 1], pv1 = psvg[pb + 2], pv2 = psvg[pb + 3];
                float sg  = sgr[m][i];
                float av  = accA[m][i];
                size_t ob = (size_t)n * DIM_Hc + MUL_Sc + 3 * u;
                out[ob + 0] = C0F * (av * pv0 + accV[0][m][i] * ps) * sg;
                out[ob + 1] = C0F * (av * pv1 + accV[1][m][i] * ps) * sg;
                out[ob + 2] = C0F * (av * pv2 + accV[2][m][i] * ps) * sg;
            }
        }
        cur ^= 1;
    }
}

extern "C" void kernel_launch(void* const* d_in, const int* in_sizes, int n_in,
                              void* d_out, int out_size, void* d_ws, size_t ws_size,
                              hipStream_t stream) {
    const float* din  = (const float*)d_in[0];
    const float* Wss  = (const float*)d_in[1];
    const float* Wvv  = (const float*)d_in[2];
    const float* Wssg = (const float*)d_in[3];
    const float* Wvvg = (const float*)d_in[4];
    const float* Wsv  = (const float*)d_in[5];
    const float* Wvs  = (const float*)d_in[6];
    const float* bias = (const float*)d_in[7];
    float* out = (float*)d_out;
    unsigned short* wt = (unsigned short*)d_ws;

    const size_t WT_SHORTS = 384 * 384 + 128 * 256 + 128 * 128;
    const size_t WT_BYTES = WT_SHORTS * 2;
    if (ws_size < WT_BYTES) return;

    int N = in_sizes[0] / IN_COLS;
    int ntiles = (N + NTS - 1) / NTS;

    prep_weights<<<((int)WT_SHORTS + 255) / 256, 256, 0, stream>>>(Wss, Wvv, Wssg, Wvvg, Wsv, Wvs, wt);

    size_t feat_bytes = (size_t)ntiles * NTS * KF * 2;
    size_t psv_bytes  = (size_t)ntiles * NTS * 4 * sizeof(float);
    size_t need = WT_BYTES + feat_bytes + psv_bytes;
    if (ws_size < need) return;   // N=100000 -> ~156MB, expected to fit

    unsigned short* featg = wt + WT_SHORTS;
    float* psvg = (float*)((char*)d_ws + WT_BYTES + feat_bytes);

    convert_feat<<<ntiles, 512, 0, stream>>>(din, featg, psvg, N);

    int gb = ntiles < GRIDB ? ntiles : GRIDB;
    gemm_pers<<<gb, 512, 0, stream>>>(featg, psvg, wt, bias, out, N, ntiles);
}